// Round 7
// baseline (32.588 us; speedup 1.0000x reference)
//
#include <hip/hip_runtime.h>
#include <math.h>

#define HWSZ   784    // 28*28
#define NCH    2048
#define NB     16
#define NWIN   1595   // 625 + 529 + 441
#define NF4    196    // 784/4
#define NCHUNK 64
#define CC     32     // 2048/64

// ---------------- Kernel 1: flat-mapped per-chunk channel sums ----------------
// tasks = NB*NCHUNK*NF4 = 200704 = 784 blocks * 256 threads, all lanes active.
// task -> (bc = b*NCHUNK+chunk, col); thread sums CC channels at stride NF4.
__global__ __launch_bounds__(256) void k_chan_partial(const float* __restrict__ in,
                                                      float* __restrict__ partial) {
    int task = blockIdx.x * 256 + threadIdx.x;
    int col  = task % NF4;
    int bc   = task / NF4;          // b*NCHUNK + chunk
    const float4* p = reinterpret_cast<const float4*>(in) + (size_t)bc * (CC * NF4) + col;
    float4 acc = make_float4(0.f, 0.f, 0.f, 0.f);
#pragma unroll 16
    for (int c = 0; c < CC; ++c) {
        float4 v = p[(size_t)c * NF4];
        acc.x += v.x; acc.y += v.y; acc.z += v.z; acc.w += v.w;
    }
    reinterpret_cast<float4*>(partial)[(size_t)bc * NF4 + col] = acc;
}

// ---------------- Kernel 2: per-(group,batch) reduce + separable pool + NMS ----------------
// grid (3, NB); each block re-reduces partials (L2-hit) then handles only its group.
__global__ __launch_bounds__(256) void k_fused(const float* __restrict__ partial,
                                               float* __restrict__ out) {
    __shared__ float xs[HWSZ];
    __shared__ float rowsum[28 * 25];   // 28 rows x n cols (n<=25)
    __shared__ float sc[625];
    int g = blockIdx.x;
    int b = blockIdx.y;
    int t = threadIdx.x;

    const int kArr[3]    = {4, 6, 8};
    const int nArr[3]    = {25, 23, 21};
    const int baseArr[3] = {0, 625, 1154};
    const int pickArr[3] = {3, 2, 1};
    const int offArr[3]  = {0, 3, 5};
    int k = kArr[g], n = nArr[g], base = baseArr[g];
    int cnt = n * n;

    // --- reduce partials -> xs (redundant per group; ~50KB L2-resident reads) ---
    if (t < NF4) {
        float4 acc = make_float4(0.f, 0.f, 0.f, 0.f);
#pragma unroll 16
        for (int ch = 0; ch < NCHUNK; ++ch) {
            float4 v = reinterpret_cast<const float4*>(
                partial + ((size_t)b * NCHUNK + ch) * HWSZ)[t];
            acc.x += v.x; acc.y += v.y; acc.z += v.z; acc.w += v.w;
        }
        reinterpret_cast<float4*>(xs)[t] = acc;
    }
    __syncthreads();

    // --- per-row sliding sums: rowsum[row*n + j] = sum_{dj<k} xs[row*28 + j+dj] ---
    int nrs = 28 * n;
    for (int idx = t; idx < nrs; idx += 256) {
        int row = idx / n, j = idx % n;
        const float* xr = xs + row * 28 + j;
        float s = 0.f;
        for (int dj = 0; dj < k; ++dj) s += xr[dj];
        rowsum[idx] = s;
    }
    __syncthreads();

    // --- windows: k adds of rowsums; write LDS copy + global window_scores ---
    float* out_win = out + 192;
    float inv = 1.f / (float)(k * k);
    for (int w = t; w < cnt; w += 256) {
        int i = w / n, j = w % n;
        const float* rp = rowsum + i * n + j;
        float s = 0.f;
        for (int di = 0; di < k; ++di) s += rp[di * n];
        s *= inv;
        sc[w] = s;
        out_win[(size_t)b * NWIN + base + w] = s;
    }
    __syncthreads();

    // --- NMS: wave 0, fully in registers ---
    if (t < 64) {
        int lane = t;
        int npick = pickArr[g], off = offArr[g];
        int kk2 = 2 * k * k;

        float s[10];
#pragma unroll
        for (int j = 0; j < 10; ++j) {
            int w = lane + 64 * j;
            s[j] = (w < cnt) ? sc[w] : -INFINITY;
        }

        for (int r = 0; r < npick; ++r) {
            // lane-local argmax (max score, tie -> smallest window index)
            float bs = -INFINITY;
            int   bi = 1 << 30;
#pragma unroll
            for (int j = 0; j < 10; ++j) {
                int w = lane + 64 * j;
                float v = s[j];
                if (v > bs || (v == bs && w < bi)) { bs = v; bi = w; }
            }
            // wave butterfly reduce
#pragma unroll
            for (int m = 1; m < 64; m <<= 1) {
                float os = __shfl_xor(bs, m);
                int   oi = __shfl_xor(bi, m);
                if (os > bs || (os == bs && oi < bi)) { bs = os; bi = oi; }
            }
            if (lane == 0) {
                out[(size_t)b * 6 + off + r]      = (float)(base + bi);
                out[96 + (size_t)b * 6 + off + r] = bs;
            }
            // suppress: IoU > 0.25  <=>  5*inter > 2*k*k (same-size boxes, exact int test)
            int pi = bi / n, pj = bi % n;
#pragma unroll
            for (int j = 0; j < 10; ++j) {
                int w = lane + 64 * j;
                int i  = w / n, jj = w % n;
                int di = i - pi;  if (di < 0) di = -di;
                int dj = jj - pj; if (dj < 0) dj = -dj;
                int iw = k - dj, ih = k - di;
                int inter = (iw > 0 && ih > 0) ? iw * ih : 0;
                if (5 * inter > kk2) s[j] = -INFINITY;
            }
        }
    }
}

extern "C" void kernel_launch(void* const* d_in, const int* in_sizes, int n_in,
                              void* d_out, int out_size, void* d_ws, size_t ws_size,
                              hipStream_t stream) {
    // input order: num_proposals, input_tensor, window_nums_sum, N_list, iou_thresholds, coordinates_cat
    const float* in = (const float*)d_in[1];
    float* out = (float*)d_out;
    float* part = (float*)d_ws;   // 16*64*784 floats = 3.2 MB

    dim3 g1(NB * NCHUNK * NF4 / 256);   // 784 blocks
    k_chan_partial<<<g1, 256, 0, stream>>>(in, part);
    dim3 g2(3, NB);
    k_fused<<<g2, 256, 0, stream>>>(part, out);
}

// Round 8
// 29.183 us; speedup vs baseline: 1.1167x; 1.1167x over previous
//
#include <hip/hip_runtime.h>
#include <math.h>

#define HWSZ   784    // 28*28
#define NCH    2048
#define NB     16
#define NWIN   1595   // 625 + 529 + 441
#define NF4    196    // 784/4
#define NCHUNK 32
#define CC     64     // 2048/32

typedef float v2f __attribute__((ext_vector_type(2)));

// ---------------- Kernel 1: per-chunk channel sums, packed-f32 accumulate ----------------
// VALU analysis: 4x v_add_f32 per float4 load caps at ~4.9 TB/s; v_pk_add_f32
// halves the add cycles -> memory-bound again. 4 chains (even/odd c) for ILP.
__global__ __launch_bounds__(256) void k_chan_partial(const float* __restrict__ in,
                                                      float* __restrict__ partial) {
    int chunk = blockIdx.x;
    int b     = blockIdx.y;
    int t     = threadIdx.x;
    if (t >= NF4) return;
    const float4* p = reinterpret_cast<const float4*>(
        in + ((size_t)b * NCH + (size_t)chunk * CC) * HWSZ) + t;
    v2f a0e = {0.f, 0.f}, a1e = {0.f, 0.f};
    v2f a0o = {0.f, 0.f}, a1o = {0.f, 0.f};
#pragma unroll 16
    for (int c = 0; c < CC; c += 2) {
        float4 v = p[(size_t)c * NF4];
        float4 w = p[(size_t)(c + 1) * NF4];
        v2f vlo = {v.x, v.y}, vhi = {v.z, v.w};
        v2f wlo = {w.x, w.y}, whi = {w.z, w.w};
        asm("v_pk_add_f32 %0, %1, %2" : "=v"(a0e) : "v"(a0e), "v"(vlo));
        asm("v_pk_add_f32 %0, %1, %2" : "=v"(a1e) : "v"(a1e), "v"(vhi));
        asm("v_pk_add_f32 %0, %1, %2" : "=v"(a0o) : "v"(a0o), "v"(wlo));
        asm("v_pk_add_f32 %0, %1, %2" : "=v"(a1o) : "v"(a1o), "v"(whi));
    }
    v2f a0, a1;
    asm("v_pk_add_f32 %0, %1, %2" : "=v"(a0) : "v"(a0e), "v"(a0o));
    asm("v_pk_add_f32 %0, %1, %2" : "=v"(a1) : "v"(a1e), "v"(a1o));
    float4 acc = make_float4(a0.x, a0.y, a1.x, a1.y);
    reinterpret_cast<float4*>(partial + ((size_t)b * NCHUNK + chunk) * HWSZ)[t] = acc;
}

// ---------------- Kernel 2: per-(group,batch) reduce + separable pool + NMS ----------------
// grid (3, NB); each block re-reduces partials (L2-hit) then handles only its group.
__global__ __launch_bounds__(256) void k_fused(const float* __restrict__ partial,
                                               float* __restrict__ out) {
    __shared__ float xs[HWSZ];
    __shared__ float rowsum[28 * 25];   // 28 rows x n cols (n<=25)
    __shared__ float sc[625];
    int g = blockIdx.x;
    int b = blockIdx.y;
    int t = threadIdx.x;

    const int kArr[3]    = {4, 6, 8};
    const int nArr[3]    = {25, 23, 21};
    const int baseArr[3] = {0, 625, 1154};
    const int pickArr[3] = {3, 2, 1};
    const int offArr[3]  = {0, 3, 5};
    int k = kArr[g], n = nArr[g], base = baseArr[g];
    int cnt = n * n;

    // --- reduce partials -> xs (redundant per group; ~100KB L2-resident reads) ---
    if (t < NF4) {
        float4 acc = make_float4(0.f, 0.f, 0.f, 0.f);
#pragma unroll 16
        for (int ch = 0; ch < NCHUNK; ++ch) {
            float4 v = reinterpret_cast<const float4*>(
                partial + ((size_t)b * NCHUNK + ch) * HWSZ)[t];
            acc.x += v.x; acc.y += v.y; acc.z += v.z; acc.w += v.w;
        }
        reinterpret_cast<float4*>(xs)[t] = acc;
    }
    __syncthreads();

    // --- per-row sliding sums: rowsum[row*n + j] = sum_{dj<k} xs[row*28 + j+dj] ---
    int nrs = 28 * n;
    for (int idx = t; idx < nrs; idx += 256) {
        int row = idx / n, j = idx % n;
        const float* xr = xs + row * 28 + j;
        float s = 0.f;
        for (int dj = 0; dj < k; ++dj) s += xr[dj];
        rowsum[idx] = s;
    }
    __syncthreads();

    // --- windows: k adds of rowsums; write LDS copy + global window_scores ---
    float* out_win = out + 192;
    float inv = 1.f / (float)(k * k);
    for (int w = t; w < cnt; w += 256) {
        int i = w / n, j = w % n;
        const float* rp = rowsum + i * n + j;
        float s = 0.f;
        for (int di = 0; di < k; ++di) s += rp[di * n];
        s *= inv;
        sc[w] = s;
        out_win[(size_t)b * NWIN + base + w] = s;
    }
    __syncthreads();

    // --- NMS: wave 0, fully in registers ---
    if (t < 64) {
        int lane = t;
        int npick = pickArr[g], off = offArr[g];
        int kk2 = 2 * k * k;

        float s[10];
#pragma unroll
        for (int j = 0; j < 10; ++j) {
            int w = lane + 64 * j;
            s[j] = (w < cnt) ? sc[w] : -INFINITY;
        }

        for (int r = 0; r < npick; ++r) {
            // lane-local argmax (max score, tie -> smallest window index)
            float bs = -INFINITY;
            int   bi = 1 << 30;
#pragma unroll
            for (int j = 0; j < 10; ++j) {
                int w = lane + 64 * j;
                float v = s[j];
                if (v > bs || (v == bs && w < bi)) { bs = v; bi = w; }
            }
            // wave butterfly reduce
#pragma unroll
            for (int m = 1; m < 64; m <<= 1) {
                float os = __shfl_xor(bs, m);
                int   oi = __shfl_xor(bi, m);
                if (os > bs || (os == bs && oi < bi)) { bs = os; bi = oi; }
            }
            if (lane == 0) {
                out[(size_t)b * 6 + off + r]      = (float)(base + bi);
                out[96 + (size_t)b * 6 + off + r] = bs;
            }
            // suppress: IoU > 0.25  <=>  5*inter > 2*k*k (same-size boxes, exact int test)
            int pi = bi / n, pj = bi % n;
#pragma unroll
            for (int j = 0; j < 10; ++j) {
                int w = lane + 64 * j;
                int i  = w / n, jj = w % n;
                int di = i - pi;  if (di < 0) di = -di;
                int dj = jj - pj; if (dj < 0) dj = -dj;
                int iw = k - dj, ih = k - di;
                int inter = (iw > 0 && ih > 0) ? iw * ih : 0;
                if (5 * inter > kk2) s[j] = -INFINITY;
            }
        }
    }
}

extern "C" void kernel_launch(void* const* d_in, const int* in_sizes, int n_in,
                              void* d_out, int out_size, void* d_ws, size_t ws_size,
                              hipStream_t stream) {
    // input order: num_proposals, input_tensor, window_nums_sum, N_list, iou_thresholds, coordinates_cat
    const float* in = (const float*)d_in[1];
    float* out = (float*)d_out;
    float* part = (float*)d_ws;   // 16*32*784 floats = 1.6 MB

    dim3 g1(NCHUNK, NB);
    k_chan_partial<<<g1, 256, 0, stream>>>(in, part);
    dim3 g2(3, NB);
    k_fused<<<g2, 256, 0, stream>>>(part, out);
}

// Round 10
// 28.671 us; speedup vs baseline: 1.1366x; 1.0179x over previous
//
#include <hip/hip_runtime.h>
#include <math.h>

#define HWSZ   784    // 28*28
#define NCH    2048
#define NB     16
#define NWIN   1595   // 625 + 529 + 441
#define NF4    196    // 784/4
#define NCHUNK 32
#define CC     64     // 2048/32

typedef float v4f __attribute__((ext_vector_type(4)));

// ---------------- Kernel 1: per-chunk channel sums, nontemporal streaming loads ----------------
__global__ __launch_bounds__(256) void k_chan_partial(const float* __restrict__ in,
                                                      float* __restrict__ partial) {
    int chunk = blockIdx.x;
    int b     = blockIdx.y;
    int t     = threadIdx.x;
    if (t >= NF4) return;
    const v4f* p = reinterpret_cast<const v4f*>(
        in + ((size_t)b * NCH + (size_t)chunk * CC) * HWSZ) + t;
    v4f a0 = {0.f, 0.f, 0.f, 0.f};
    v4f a1 = {0.f, 0.f, 0.f, 0.f};
#pragma unroll 16
    for (int c = 0; c < CC; c += 2) {
        v4f v = __builtin_nontemporal_load(p + (size_t)c * NF4);
        v4f w = __builtin_nontemporal_load(p + (size_t)(c + 1) * NF4);
        a0 += v;
        a1 += w;
    }
    v4f acc = a0 + a1;
    reinterpret_cast<v4f*>(partial + ((size_t)b * NCHUNK + chunk) * HWSZ)[t] = acc;
}

// ---------------- Kernel 2: per-(group,batch) reduce + separable pool + NMS ----------------
// grid (3, NB); each block re-reduces partials (L2/L3-hit) then handles only its group.
__global__ __launch_bounds__(256) void k_fused(const float* __restrict__ partial,
                                               float* __restrict__ out) {
    __shared__ float xs[HWSZ];
    __shared__ float rowsum[28 * 25];   // 28 rows x n cols (n<=25)
    __shared__ float sc[625];
    int g = blockIdx.x;
    int b = blockIdx.y;
    int t = threadIdx.x;

    const int kArr[3]    = {4, 6, 8};
    const int nArr[3]    = {25, 23, 21};
    const int baseArr[3] = {0, 625, 1154};
    const int pickArr[3] = {3, 2, 1};
    const int offArr[3]  = {0, 3, 5};
    int k = kArr[g], n = nArr[g], base = baseArr[g];
    int cnt = n * n;

    // --- reduce partials -> xs ---
    if (t < NF4) {
        float4 acc = make_float4(0.f, 0.f, 0.f, 0.f);
#pragma unroll 16
        for (int ch = 0; ch < NCHUNK; ++ch) {
            float4 v = reinterpret_cast<const float4*>(
                partial + ((size_t)b * NCHUNK + ch) * HWSZ)[t];
            acc.x += v.x; acc.y += v.y; acc.z += v.z; acc.w += v.w;
        }
        reinterpret_cast<float4*>(xs)[t] = acc;
    }
    __syncthreads();

    // --- per-row sliding sums: rowsum[row*n + j] = sum_{dj<k} xs[row*28 + j+dj] ---
    int nrs = 28 * n;
    for (int idx = t; idx < nrs; idx += 256) {
        int row = idx / n, j = idx % n;
        const float* xr = xs + row * 28 + j;
        float s = 0.f;
        for (int dj = 0; dj < k; ++dj) s += xr[dj];
        rowsum[idx] = s;
    }
    __syncthreads();

    // --- windows: k adds of rowsums; write LDS copy + global window_scores ---
    float* out_win = out + 192;
    float inv = 1.f / (float)(k * k);
    for (int w = t; w < cnt; w += 256) {
        int i = w / n, j = w % n;
        const float* rp = rowsum + i * n + j;
        float s = 0.f;
        for (int di = 0; di < k; ++di) s += rp[di * n];
        s *= inv;
        sc[w] = s;
        out_win[(size_t)b * NWIN + base + w] = s;
    }
    __syncthreads();

    // --- NMS: wave 0, fully in registers ---
    if (t < 64) {
        int lane = t;
        int npick = pickArr[g], off = offArr[g];
        int kk2 = 2 * k * k;

        float s[10];
#pragma unroll
        for (int j = 0; j < 10; ++j) {
            int w = lane + 64 * j;
            s[j] = (w < cnt) ? sc[w] : -INFINITY;
        }

        for (int r = 0; r < npick; ++r) {
            // lane-local argmax (max score, tie -> smallest window index)
            float bs = -INFINITY;
            int   bi = 1 << 30;
#pragma unroll
            for (int j = 0; j < 10; ++j) {
                int w = lane + 64 * j;
                float v = s[j];
                if (v > bs || (v == bs && w < bi)) { bs = v; bi = w; }
            }
            // wave butterfly reduce
#pragma unroll
            for (int m = 1; m < 64; m <<= 1) {
                float os = __shfl_xor(bs, m);
                int   oi = __shfl_xor(bi, m);
                if (os > bs || (os == bs && oi < bi)) { bs = os; bi = oi; }
            }
            if (lane == 0) {
                out[(size_t)b * 6 + off + r]      = (float)(base + bi);
                out[96 + (size_t)b * 6 + off + r] = bs;
            }
            // suppress: IoU > 0.25  <=>  5*inter > 2*k*k (same-size boxes, exact int test)
            int pi = bi / n, pj = bi % n;
#pragma unroll
            for (int j = 0; j < 10; ++j) {
                int w = lane + 64 * j;
                int i  = w / n, jj = w % n;
                int di = i - pi;  if (di < 0) di = -di;
                int dj = jj - pj; if (dj < 0) dj = -dj;
                int iw = k - dj, ih = k - di;
                int inter = (iw > 0 && ih > 0) ? iw * ih : 0;
                if (5 * inter > kk2) s[j] = -INFINITY;
            }
        }
    }
}

extern "C" void kernel_launch(void* const* d_in, const int* in_sizes, int n_in,
                              void* d_out, int out_size, void* d_ws, size_t ws_size,
                              hipStream_t stream) {
    // input order: num_proposals, input_tensor, window_nums_sum, N_list, iou_thresholds, coordinates_cat
    const float* in = (const float*)d_in[1];
    float* out = (float*)d_out;
    float* part = (float*)d_ws;   // 16*32*784 floats = 1.6 MB

    dim3 g1(NCHUNK, NB);
    k_chan_partial<<<g1, 256, 0, stream>>>(in, part);
    dim3 g2(3, NB);
    k_fused<<<g2, 256, 0, stream>>>(part, out);
}